// Round 6
// baseline (433.761 us; speedup 1.0000x reference)
//
#include <hip/hip_runtime.h>

// PE constants:
//   w_j   = 10000^(-j/256) = exp2f(PE_C2 * j),  PE_C2 = -log2(10000)/256
//   angle = i * w_j ;  pe[i, 2j] = sin(angle), pe[i, 2j+1] = cos(angle)
// Columns 510/511 stay zero (reference uses n_pairs = 255).
// NOTE (R2 post-mortem): do NOT replace the second exp2f with a hand-derived
// ratio constant — a 5.7e-6 constant error became 0.73 absmax at i=131071.
#define PE_C2 (-0.051905126482615034f)

typedef float vfloat4 __attribute__((ext_vector_type(4)));

#define NTHR          256
#define ROWS_PER_BLK  64
#define UNROLL        4

// R6: MEASUREMENT ROUND — idempotent double-dispatch.
//  Findings so far (all neutral => falsified as bottleneck): token dependency
//  chain / MLP depth (R2), NT vs plain stores (R4 tile-parity A/B), occupancy
//  16 vs 32 waves/CU (R5). Our kernel NEVER appears in rocprof top-5 (all
//  slots are ~166 us harness fills), so its true duration T is unknown:
//    World A: T ~ 150-165 us (mixed-stream wall, ~100 us headroom)
//    World B: T ~  50-90 us (near floor; dur_us dominated by harness fill)
//  This round launches the IDENTICAL kernel twice (output written twice with
//  identical values — deterministic, correct). dur_us(R6) - dur_us(R5) = T
//  (warm-cache) + ~5 us launch overhead. Decides World A vs B.
__global__ __launch_bounds__(NTHR, 8) void pe_gather_kernel(
    const int* __restrict__ token_ids,
    const vfloat4* __restrict__ emb,      // emb_table viewed as [VOCAB][128] float4
    vfloat4* __restrict__ out,            // [SEQ][128] float4
    int seq)                              // number of rows (131072)
{
    __shared__ int s_tok[ROWS_PER_BLK];

    const int base = blockIdx.x * ROWS_PER_BLK;
    const int v    = threadIdx.x & 127;   // float4 column slot
    const int rsub = threadIdx.x >> 7;    // 0 or 1: even/odd rows of the block

    if (threadIdx.x < ROWS_PER_BLK) {
        const int idx = base + threadIdx.x;
        s_tok[threadIdx.x] = (idx < seq) ? token_ids[idx] : 0;
    }

    // loop-invariant frequencies (keep exp2f form — see R2 note above)
    const float w0 = exp2f(PE_C2 * (float)(2 * v));
    const float w1 = exp2f(PE_C2 * (float)(2 * v + 1));
    const bool  full = (v < 127);         // v==127: second pair is j=255 -> pe 0

    __syncthreads();

    // rows covered: rsub + {0,2,...,62}; 8 outer iters x 4 unrolled rows.
    for (int kk = rsub; kk < ROWS_PER_BLK; kk += 2 * UNROLL) {
        vfloat4 e[UNROLL];
        #pragma unroll
        for (int u = 0; u < UNROLL; ++u) {
            const int tok = s_tok[kk + 2 * u];          // LDS broadcast
            e[u] = emb[(size_t)tok * 128 + v];          // independent gathers
        }
        #pragma unroll
        for (int u = 0; u < UNROLL; ++u) {
            const int row = base + kk + 2 * u;
            const float fi = (float)row;

            float s0, c0;
            __sincosf(fi * w0, &s0, &c0);

            vfloat4 r;
            r.x = e[u].x + s0;
            r.y = e[u].y + c0;

            if (full) {
                float s1, c1;
                __sincosf(fi * w1, &s1, &c1);
                r.z = e[u].z + s1;
                r.w = e[u].w + c1;
            } else {
                r.z = e[u].z;
                r.w = e[u].w;
            }

            if (row < seq)
                __builtin_nontemporal_store(r, &out[(size_t)row * 128 + v]);
        }
    }
}

extern "C" void kernel_launch(void* const* d_in, const int* in_sizes, int n_in,
                              void* d_out, int out_size, void* d_ws, size_t ws_size,
                              hipStream_t stream) {
    const int*   token_ids = (const int*)d_in[0];
    const float* emb_table = (const float*)d_in[1];

    const int seq    = in_sizes[0];                    // 131072
    const int nblk   = (seq + ROWS_PER_BLK - 1) / ROWS_PER_BLK;  // 2048

    // Dispatch 1: the real computation.
    pe_gather_kernel<<<nblk, NTHR, 0, stream>>>(
        token_ids, (const vfloat4*)emb_table, (vfloat4*)d_out, seq);
    // Dispatch 2: IDENTICAL, idempotent — exists only to measure the kernel's
    // warm-cache duration via dur_us(R6) - dur_us(R5). Remove next round.
    pe_gather_kernel<<<nblk, NTHR, 0, stream>>>(
        token_ids, (const vfloat4*)emb_table, (vfloat4*)d_out, seq);
}

// Round 7
// 359.292 us; speedup vs baseline: 1.2073x; 1.2073x over previous
//
#include <hip/hip_runtime.h>

// PE constants:
//   w_j   = 10000^(-j/256) = exp2f(PE_C2 * j),  PE_C2 = -log2(10000)/256
//   angle = i * w_j ;  pe[i, 2j] = sin(angle), pe[i, 2j+1] = cos(angle)
// Columns 510/511 stay zero (reference uses n_pairs = 255).
// NOTE (R2 post-mortem): do NOT replace the second exp2f with a hand-derived
// ratio constant — a 5.7e-6 constant error became 0.73 absmax at i=131071.
#define PE_C2 (-0.051905126482615034f)

typedef float vfloat4 __attribute__((ext_vector_type(4)));

#define NTHR          256
#define ROWS_PER_BLK  64
#define UNROLL        4
#define VOCAB         50257
#define TABLE_F4      (VOCAB * 128)   // 6,432,896 float4 elements in emb table

// R7: cold-cache prefetch round. Session findings:
//  - Falsified as bottleneck: token dep chain/MLP (R2), NT stores (R4 A/B),
//    occupancy 16 vs 32 waves/CU (R5).
//  - R6 double-dispatch measurement: T_warm ~= 72 us (433.8 - 356.1 - ~5).
//    Scored dispatch is COLD: harness's 1 GiB poison fill (~166 us, in every
//    timed iter) evicts the 256 MiB L3, forcing a 103 MB compulsory table
//    re-fetch via random 2 KiB gathers (degraded HBM efficiency + miss
//    stalls). Score = Fixed_harness + T_cold, T_cold in [~100, ~165].
//  - This round: distributed sequential table prefetch at kernel start.
//    Whole grid is co-resident (4 waves x 8 blocks/CU at 64-VGPR cap), so
//    2048 blocks each streaming ~50 KB = full-BW sequential sweep of the
//    103 MB table into memory-side L3 in ~16-25 us, concurrent with early
//    gathers. Gathers then hit warm L3 instead of stalling on HBM.
//    No barrier needed (performance hint only). asm keep-alive prevents DCE.
__global__ __launch_bounds__(NTHR, 8) void pe_gather_kernel(
    const int* __restrict__ token_ids,
    const vfloat4* __restrict__ emb,      // emb_table viewed as [VOCAB][128] float4
    vfloat4* __restrict__ out,            // [SEQ][128] float4
    int seq)                              // number of rows (131072)
{
    __shared__ int s_tok[ROWS_PER_BLK];

    const int base = blockIdx.x * ROWS_PER_BLK;
    const int v    = threadIdx.x & 127;   // float4 column slot
    const int rsub = threadIdx.x >> 7;    // 0 or 1: even/odd rows of the block

    if (threadIdx.x < ROWS_PER_BLK) {
        const int idx = base + threadIdx.x;
        s_tok[threadIdx.x] = (idx < seq) ? token_ids[idx] : 0;
    }

    // ---- Phase 0: distributed sequential table prefetch (L3 warmer) ----
    {
        const size_t nthreads = (size_t)gridDim.x * NTHR;      // 524288
        vfloat4 acc = {0.f, 0.f, 0.f, 0.f};
        #pragma unroll 4
        for (size_t i = (size_t)blockIdx.x * NTHR + threadIdx.x;
             i < (size_t)TABLE_F4; i += nthreads) {
            const vfloat4 t = emb[i];                          // sequential, coalesced
            acc.x += t.x; acc.y += t.y; acc.z += t.z; acc.w += t.w;
        }
        // Keep the prefetch live without storing anything (rule #17).
        asm volatile("" :: "v"(acc.x), "v"(acc.y), "v"(acc.z), "v"(acc.w));
    }

    // loop-invariant frequencies (keep exp2f form — see R2 note above)
    const float w0 = exp2f(PE_C2 * (float)(2 * v));
    const float w1 = exp2f(PE_C2 * (float)(2 * v + 1));
    const bool  full = (v < 127);         // v==127: second pair is j=255 -> pe 0

    __syncthreads();

    // rows covered: rsub + {0,2,...,62}; 8 outer iters x 4 unrolled rows.
    for (int kk = rsub; kk < ROWS_PER_BLK; kk += 2 * UNROLL) {
        vfloat4 e[UNROLL];
        #pragma unroll
        for (int u = 0; u < UNROLL; ++u) {
            const int tok = s_tok[kk + 2 * u];          // LDS broadcast
            e[u] = emb[(size_t)tok * 128 + v];          // independent gathers
        }
        #pragma unroll
        for (int u = 0; u < UNROLL; ++u) {
            const int row = base + kk + 2 * u;
            const float fi = (float)row;

            float s0, c0;
            __sincosf(fi * w0, &s0, &c0);

            vfloat4 r;
            r.x = e[u].x + s0;
            r.y = e[u].y + c0;

            if (full) {
                float s1, c1;
                __sincosf(fi * w1, &s1, &c1);
                r.z = e[u].z + s1;
                r.w = e[u].w + c1;
            } else {
                r.z = e[u].z;
                r.w = e[u].w;
            }

            if (row < seq)
                __builtin_nontemporal_store(r, &out[(size_t)row * 128 + v]);
        }
    }
}

extern "C" void kernel_launch(void* const* d_in, const int* in_sizes, int n_in,
                              void* d_out, int out_size, void* d_ws, size_t ws_size,
                              hipStream_t stream) {
    const int*   token_ids = (const int*)d_in[0];
    const float* emb_table = (const float*)d_in[1];

    const int seq    = in_sizes[0];                    // 131072
    const int nblk   = (seq + ROWS_PER_BLK - 1) / ROWS_PER_BLK;  // 2048

    pe_gather_kernel<<<nblk, NTHR, 0, stream>>>(
        token_ids, (const vfloat4*)emb_table, (vfloat4*)d_out, seq);
}